// Round 12
// baseline (395.238 us; speedup 1.0000x reference)
//
#include <hip/hip_runtime.h>

#define B  4
#define T  2048
#define D  1024
#define NH 16
#define DH 64
#define MROWS (B*T)   // 8192

typedef __attribute__((ext_vector_type(8))) short bf16x8;
typedef __attribute__((ext_vector_type(4))) float f32x4;
typedef __attribute__((ext_vector_type(4))) unsigned short u16x4;
typedef __attribute__((address_space(1))) const void gvoid;
typedef __attribute__((address_space(3))) void lvoid;

#define C_EXP 0.18033688011112042f   // 0.125 * log2(e)
// V-tile swizzle: must spread when dh = 4*lq+j (write) AND dh = dt*16+lq (read)
#define VSWZ(dh) (((((dh) ^ ((dh) >> 2)) & 7)) << 4)

__device__ inline unsigned short f2bf(float f) {
    union { float f; unsigned int u; } v; v.f = f;
    unsigned int r = v.u + 0x7fff + ((v.u >> 16) & 1);   // RNE
    return (unsigned short)(r >> 16);
}
__device__ inline float bf2f(unsigned short u) {
    union { unsigned int u; float f; } v; v.u = ((unsigned int)u) << 16;
    return v.f;
}
__device__ inline float exp2_fast(float x) {
    float r;
    asm("v_exp_f32 %0, %1" : "=v"(r) : "v"(x));   // D = 2^S0
    return r;
}

// ---------------------------------------------------------------------------
// Split fp32 array into bf16 hi + bf16 lo (lo = bf16(x - hi)).
// ---------------------------------------------------------------------------
__global__ __launch_bounds__(256)
void split_f32(const float* __restrict__ in, unsigned short* __restrict__ hi,
               unsigned short* __restrict__ lo, int n4) {
    for (int i = blockIdx.x * 256 + threadIdx.x; i < n4; i += gridDim.x * 256) {
        const float4 v = ((const float4*)in)[i];
        ushort4 h, l;
        h.x = f2bf(v.x); l.x = f2bf(v.x - bf2f(h.x));
        h.y = f2bf(v.y); l.y = f2bf(v.y - bf2f(h.y));
        h.z = f2bf(v.z); l.z = f2bf(v.z - bf2f(h.z));
        h.w = f2bf(v.w); l.w = f2bf(v.w - bf2f(h.w));
        ((ushort4*)hi)[i] = h;
        ((ushort4*)lo)[i] = l;
    }
}

// ---------------------------------------------------------------------------
// Transpose (K x N fp32) -> (N x K) bf16 hi/lo, 32x32 LDS tiles.
// ---------------------------------------------------------------------------
__global__ __launch_bounds__(256)
void split_tr(const float* __restrict__ Wm, unsigned short* __restrict__ hi,
              unsigned short* __restrict__ lo, int K, int N) {
    __shared__ float Tl[32][36];
    const int nt = blockIdx.x * 32, kt = blockIdx.y * 32;
    const int t = threadIdx.x;
    {
        const int r = t >> 3, c = (t & 7) * 4;
        const float4 v = *(const float4*)&Wm[(size_t)(kt + r) * N + nt + c];
        Tl[r][c] = v.x; Tl[r][c + 1] = v.y; Tl[r][c + 2] = v.z; Tl[r][c + 3] = v.w;
    }
    __syncthreads();
    {
        const int nl = t >> 3, k4 = (t & 7) * 4;
        const float v0 = Tl[k4 + 0][nl], v1 = Tl[k4 + 1][nl];
        const float v2 = Tl[k4 + 2][nl], v3 = Tl[k4 + 3][nl];
        ushort4 h, l;
        h.x = f2bf(v0); l.x = f2bf(v0 - bf2f(h.x));
        h.y = f2bf(v1); l.y = f2bf(v1 - bf2f(h.y));
        h.z = f2bf(v2); l.z = f2bf(v2 - bf2f(h.z));
        h.w = f2bf(v3); l.w = f2bf(v3 - bf2f(h.w));
        const size_t o = (size_t)(nt + nl) * K + kt + k4;
        *(ushort4*)&hi[o] = h;
        *(ushort4*)&lo[o] = l;
    }
}

// ---------------------------------------------------------------------------
// Split-bf16 MFMA GEMM: C = A@B, 3 MFMA passes (hi*hi + hi*lo + lo*hi).
// A ~ Ahi+Alo (MxK), B^T ~ Bthi+Btlo (NxK). BM=128, BN=256, BK=32,
// 4 waves (2M x 2N), per-wave tile 64x128 -> reads/MFMA = 0.25 (was 0.33),
// flipping the kernel from LDS-port-bound to MFMA-bound. 2-phase dbuf,
// ONE __syncthreads per K-tile (no intra-tile barriers): compiler streams
// B-fragment ds_reads under the MFMA bursts with counted lgkmcnt.
// ---------------------------------------------------------------------------
template<bool OUT_BF16>
__global__ __launch_bounds__(256, 2)
void gemm_split(const unsigned short* __restrict__ Ahi, const unsigned short* __restrict__ Alo,
                const unsigned short* __restrict__ Bthi, const unsigned short* __restrict__ Btlo,
                void* __restrict__ Cout, int M, int N, int K) {
    __shared__ unsigned char As[2][128 * 128];   // 128 rows x (hi 64B | lo 64B)
    __shared__ unsigned char Bs[2][256 * 128];   // 256 rows x (hi 64B | lo 64B)
    const int tid  = threadIdx.x;
    const int w    = tid >> 6;        // 0..3
    const int lane = tid & 63;
    const int lq   = lane & 15;
    const int lk   = lane >> 4;
    const int wm   = w >> 1;          // 0..1 -> 64-row band
    const int wn   = w & 1;           // 0..1 -> 128-col band

    // XCD-aware bijective swizzle (nwg % 8 == 0 for both launches).
    const int gx  = gridDim.x;
    const int nwg = gx * gridDim.y;
    int lin = blockIdx.y * gx + blockIdx.x;
    lin = (lin & 7) * (nwg >> 3) + (lin >> 3);
    const int bm = (lin / gx) * 128;
    const int bn = (lin % gx) * 256;

    // pre-swizzled staging source pattern: lane l -> LDS (row=l>>3, slot=l&7);
    // content must be chunk (slot ^ row) of that row (rows 8-aligned).
    const int srow   = lane >> 3;
    const int sidx   = (lane & 7) ^ srow;   // 0..7: 0-3 = hi chunks, 4-7 = lo
    const int shalf  = sidx >> 2;
    const int schunk = sidx & 3;
    const unsigned short* aPtr = (shalf ? Alo : Ahi) + (size_t)(bm + w * 32 + srow) * K + schunk * 8;
    const unsigned short* bPtr = (shalf ? Btlo : Bthi) + (size_t)(bn + w * 64 + srow) * K + schunk * 8;

    f32x4 acc[4][8];
    #pragma unroll
    for (int m = 0; m < 4; ++m)
        #pragma unroll
        for (int n = 0; n < 8; ++n) acc[m][n] = f32x4{0.f, 0.f, 0.f, 0.f};

    // ---- prologue: stage K-tile 0 into buffer 0 (A: 4 instr, B: 8 instr) ----
    #pragma unroll
    for (int i = 0; i < 4; ++i)
        __builtin_amdgcn_global_load_lds((gvoid*)(aPtr + (size_t)i * 8 * K),
                                         (lvoid*)&As[0][(w * 32 + i * 8) * 128], 16, 0, 0);
    #pragma unroll
    for (int i = 0; i < 8; ++i)
        __builtin_amdgcn_global_load_lds((gvoid*)(bPtr + (size_t)i * 8 * K),
                                         (lvoid*)&Bs[0][(w * 64 + i * 8) * 128], 16, 0, 0);
    __syncthreads();

    int cur = 0;
    for (int k0 = 0; k0 < K; k0 += 32) {
        // ---- issue next-tile staging early (hides under this tile's MFMA) ----
        if (k0 + 32 < K) {
            #pragma unroll
            for (int i = 0; i < 4; ++i)
                __builtin_amdgcn_global_load_lds(
                    (gvoid*)(aPtr + (size_t)i * 8 * K + k0 + 32),
                    (lvoid*)&As[cur ^ 1][(w * 32 + i * 8) * 128], 16, 0, 0);
            #pragma unroll
            for (int i = 0; i < 8; ++i)
                __builtin_amdgcn_global_load_lds(
                    (gvoid*)(bPtr + (size_t)i * 8 * K + k0 + 32),
                    (lvoid*)&Bs[cur ^ 1][(w * 64 + i * 8) * 128], 16, 0, 0);
        }

        // ---- A fragments once per K-tile (held in VGPR, reused over 8 n) ----
        bf16x8 ah[4], al[4];
        #pragma unroll
        for (int m = 0; m < 4; ++m) {
            const int row = wm * 64 + m * 16 + lq;
            const int sw  = row & 7;
            ah[m] = *(const bf16x8*)&As[cur][row * 128 + ((lk ^ sw) << 4)];
            al[m] = *(const bf16x8*)&As[cur][row * 128 + (((4 + lk) ^ sw) << 4)];
        }
        // ---- stream over 8 B sub-tiles: 2 ds_reads -> 12 MFMA each ----
        #pragma unroll
        for (int n = 0; n < 8; ++n) {
            const int row = wn * 128 + n * 16 + lq;
            const int sw  = row & 7;
            const bf16x8 bh = *(const bf16x8*)&Bs[cur][row * 128 + ((lk ^ sw) << 4)];
            const bf16x8 bl = *(const bf16x8*)&Bs[cur][row * 128 + (((4 + lk) ^ sw) << 4)];
            #pragma unroll
            for (int m = 0; m < 4; ++m) {
                acc[m][n] = __builtin_amdgcn_mfma_f32_16x16x32_bf16(ah[m], bh, acc[m][n], 0, 0, 0);
                acc[m][n] = __builtin_amdgcn_mfma_f32_16x16x32_bf16(ah[m], bl, acc[m][n], 0, 0, 0);
                acc[m][n] = __builtin_amdgcn_mfma_f32_16x16x32_bf16(al[m], bh, acc[m][n], 0, 0, 0);
            }
        }
        __syncthreads();   // single barrier: drains staging, protects buf reuse
        cur ^= 1;
    }

    #pragma unroll
    for (int m = 0; m < 4; ++m)
        #pragma unroll
        for (int ri = 0; ri < 4; ++ri) {
            const int row = bm + wm * 64 + m * 16 + lk * 4 + ri;
            #pragma unroll
            for (int n = 0; n < 8; ++n) {
                const int col = bn + wn * 128 + n * 16 + lq;
                if (OUT_BF16)
                    ((unsigned short*)Cout)[(size_t)row * N + col] = f2bf(acc[m][n][ri]);
                else
                    ((float*)Cout)[(size_t)row * N + col] = acc[m][n][ri];
            }
        }
}

// ---------------------------------------------------------------------------
// bf16-MFMA flash attention (unchanged). 8 waves, Q-tile 128, KV-tile 64,
// double-buffered K (global_load_lds) and V (reg-staged transpose).
// ---------------------------------------------------------------------------
__global__ __launch_bounds__(512)
void attn_mfma(const unsigned short* __restrict__ qkv,
               unsigned short* __restrict__ yhi, unsigned short* __restrict__ ylo) {
    const int bh  = blockIdx.y;
    const int b   = bh / NH;
    const int h   = bh % NH;
    const int qt  = blockIdx.x;           // Q-tile of 128 rows
    const int tid = threadIdx.x;
    const int w    = tid >> 6;            // 0..7
    const int lane = tid & 63;
    const int lq   = lane & 15;
    const int lk   = lane >> 4;

    __shared__ unsigned char Ks [2][64 * 128];  // bf16 [key][dh], swizzled, dbuf
    __shared__ unsigned char Vts[2][64 * 128];  // bf16 [dh][key], VSWZ, dbuf
    __shared__ unsigned char QPs[128 * 128];    // Q tile 128 rows; then P (8 x 2KB)

    // ---- stage Q (bf16 copy, swizzled): 1024 chunks of 16B, 512 thr x 2 ----
    #pragma unroll
    for (int it = 0; it < 2; ++it) {
        const int c   = tid + 512 * it;
        const int row = c >> 3, slot = c & 7;
        const bf16x8 v = *(const bf16x8*)&qkv[(size_t)(b * T + qt * 128 + row) * (3 * D) + h * DH + slot * 8];
        *(bf16x8*)&QPs[row * 128 + ((slot ^ (row & 7)) << 4)] = v;
    }

    // per-lane pre-swizzled source for K global_load_lds (1 instr/wave, 8 rows)
    const int srow   = lane >> 3;
    const int schunk = (lane & 7) ^ srow;
    const unsigned short* kBase = qkv + (size_t)(b * T + w * 8 + srow) * (3 * D) + D + h * DH + schunk * 8;
    // V staging: thread covers keys w*8+lk*2+{0,1}, dh lq*4..lq*4+3
    const unsigned short* vBase = qkv + (size_t)(b * T + w * 8 + lk * 2) * (3 * D) + 2 * D + h * DH + lq * 4;

    // ---- prologue: stage tile 0 into buffer 0 ----
    __builtin_amdgcn_global_load_lds((gvoid*)kBase, (lvoid*)&Ks[0][(w * 8) * 128], 16, 0, 0);
    u16x4 vr[2];
    #pragma unroll
    for (int i = 0; i < 2; ++i)
        vr[i] = *(const u16x4*)(vBase + (size_t)i * (3 * D));
    #pragma unroll
    for (int j = 0; j < 4; ++j) {
        const int dh = lq * 4 + j;
        const unsigned int pk = (unsigned int)vr[0][j] | ((unsigned int)vr[1][j] << 16);
        *(unsigned int*)&Vts[0][(dh * 128 + w * 16 + lk * 4) ^ VSWZ(dh)] = pk;
    }
    __syncthreads();

    // ---- Q fragments (wave w owns rows w*16..w*16+15) ----
    bf16x8 qf[2];
    #pragma unroll
    for (int ks = 0; ks < 2; ++ks) {
        const int row = w * 16 + lq;
        qf[ks] = *(const bf16x8*)&QPs[row * 128 + (((ks * 4 + lk) ^ (row & 7)) << 4)];
    }

    f32x4 o[4];
    #pragma unroll
    for (int dt = 0; dt < 4; ++dt) o[dt] = f32x4{0.f, 0.f, 0.f, 0.f};
    float m_r = -1e30f, l_r = 0.f;

    unsigned char* Pw = &QPs[w * 2048];

    for (int t = 0; t < T / 64; ++t) {
        const int c = t & 1;
        const bool more = (t + 1 < T / 64);
        // ---- issue next-tile staging early (hides under compute) ----
        if (more) {
            const int ktn = (t + 1) * 64;
            __builtin_amdgcn_global_load_lds((gvoid*)(kBase + (size_t)ktn * (3 * D)),
                                             (lvoid*)&Ks[c ^ 1][(w * 8) * 128], 16, 0, 0);
            #pragma unroll
            for (int i = 0; i < 2; ++i)
                vr[i] = *(const u16x4*)(vBase + (size_t)(ktn + i) * (3 * D));
        }

        // ---- S^T = K Q (swapped): lane owns 16 logits of query lq ----
        f32x4 s[4];
        #pragma unroll
        for (int ct = 0; ct < 4; ++ct) s[ct] = f32x4{0.f, 0.f, 0.f, 0.f};
        __builtin_amdgcn_s_setprio(1);
        #pragma unroll
        for (int ks = 0; ks < 2; ++ks) {
            #pragma unroll
            for (int ct = 0; ct < 4; ++ct) {
                const int key = ct * 16 + lq;
                const bf16x8 kf = *(const bf16x8*)&Ks[c][key * 128 + (((ks * 4 + lk) ^ (key & 7)) << 4)];
                s[ct] = __builtin_amdgcn_mfma_f32_16x16x32_bf16(kf, qf[ks], s[ct], 0, 0, 0);
            }
        }
        __builtin_amdgcn_s_setprio(0);

        // ---- online softmax (raw-logit domain) ----
        float v16 = s[0][0];
        #pragma unroll
        for (int ct = 0; ct < 4; ++ct)
            #pragma unroll
            for (int r = 0; r < 4; ++r) v16 = fmaxf(v16, s[ct][r]);
        v16 = fmaxf(v16, __shfl_xor(v16, 16));
        v16 = fmaxf(v16, __shfl_xor(v16, 32));
        if (__any(v16 > m_r)) {
            const float mnew = fmaxf(m_r, v16);
            const float corr = exp2_fast((m_r - mnew) * C_EXP);
            m_r = mnew;
            l_r *= corr;
            float corrO[4];
            #pragma unroll
            for (int r = 0; r < 4; ++r) corrO[r] = __shfl(corr, lk * 4 + r);
            #pragma unroll
            for (int dt = 0; dt < 4; ++dt)
                #pragma unroll
                for (int r = 0; r < 4; ++r) o[dt][r] *= corrO[r];
        }
        const float mC = m_r * C_EXP;
        float p[4][4];
        float tsum = 0.f;
        #pragma unroll
        for (int ct = 0; ct < 4; ++ct)
            #pragma unroll
            for (int r = 0; r < 4; ++r) {
                p[ct][r] = exp2_fast(__builtin_fmaf(s[ct][r], C_EXP, -mC));
                tsum += p[ct][r];
            }
        tsum += __shfl_xor(tsum, 16);
        tsum += __shfl_xor(tsum, 32);
        l_r += tsum;

        // ---- P pack (v_cvt_pk_bf16_f32) + 4x ds_write_b64 ----
        #pragma unroll
        for (int ct = 0; ct < 4; ++ct) {
            uint2 pk2;
            asm("v_cvt_pk_bf16_f32 %0, %1, %2" : "=v"(pk2.x) : "v"(p[ct][0]), "v"(p[ct][1]));
            asm("v_cvt_pk_bf16_f32 %0, %1, %2" : "=v"(pk2.y) : "v"(p[ct][2]), "v"(p[ct][3]));
            *(uint2*)&Pw[(lq * 128 + ct * 32 + lk * 8) ^ ((lq & 7) << 4)] = pk2;
        }
        asm volatile("s_waitcnt lgkmcnt(0)" ::: "memory");
        __builtin_amdgcn_sched_barrier(0);

        // ---- O += P V ----
        __builtin_amdgcn_s_setprio(1);
        #pragma unroll
        for (int ks = 0; ks < 2; ++ks) {
            const bf16x8 pf = *(const bf16x8*)&Pw[(lq * 128 + ks * 64 + lk * 16) ^ ((lq & 7) << 4)];
            #pragma unroll
            for (int dt = 0; dt < 4; ++dt) {
                const int dh = dt * 16 + lq;
                const bf16x8 vf = *(const bf16x8*)&Vts[c][(dh * 128 + ks * 64 + lk * 16) ^ VSWZ(dh)];
                o[dt] = __builtin_amdgcn_mfma_f32_16x16x32_bf16(pf, vf, o[dt], 0, 0, 0);
            }
        }
        __builtin_amdgcn_s_setprio(0);

        // ---- write next V tile into other buffer (vmcnt auto-waited) ----
        if (more) {
            #pragma unroll
            for (int j = 0; j < 4; ++j) {
                const int dh = lq * 4 + j;
                const unsigned int pk = (unsigned int)vr[0][j] | ((unsigned int)vr[1][j] << 16);
                *(unsigned int*)&Vts[c ^ 1][(dh * 128 + w * 16 + lk * 4) ^ VSWZ(dh)] = pk;
            }
        }
        __syncthreads();   // one barrier per tile
    }

    // ---- epilogue: O/l -> y hi/lo bf16 ----
    const float inv = 1.0f / l_r;
    float invO[4];
    #pragma unroll
    for (int r = 0; r < 4; ++r) invO[r] = __shfl(inv, lk * 4 + r);
    #pragma unroll
    for (int r = 0; r < 4; ++r) {
        const int row = qt * 128 + w * 16 + lk * 4 + r;
        const size_t base = (size_t)(b * T + row) * D + h * DH;
        #pragma unroll
        for (int dt = 0; dt < 4; ++dt) {
            const float val = o[dt][r] * invO[r];
            const unsigned short hv = f2bf(val);
            yhi[base + dt * 16 + lq] = hv;
            ylo[base + dt * 16 + lq] = f2bf(val - bf2f(hv));
        }
    }
}

// ---------------------------------------------------------------------------
extern "C" void kernel_launch(void* const* d_in, const int* in_sizes, int n_in,
                              void* d_out, int out_size, void* d_ws, size_t ws_size,
                              hipStream_t stream) {
    const float* x     = (const float*)d_in[0];
    const float* w_qkv = (const float*)d_in[1];
    const float* w_out = (const float*)d_in[2];

    unsigned short* Xhi = (unsigned short*)d_ws;              // M*D (reused as Yhi)
    unsigned short* Xlo = Xhi + (size_t)MROWS * D;            // M*D (reused as Ylo)
    unsigned short* Wqh = Xlo + (size_t)MROWS * D;            // 3D*D (N x K)
    unsigned short* Wql = Wqh + (size_t)3 * D * D;
    unsigned short* Woh = Wql + (size_t)3 * D * D;            // D*D
    unsigned short* Wol = Woh + (size_t)D * D;
    unsigned short* QKV = Wol + (size_t)D * D;                // M*3D bf16

    split_f32<<<2048, 256, 0, stream>>>(x, Xhi, Xlo, MROWS * D / 4);
    split_tr<<<dim3(3 * D / 32, D / 32), 256, 0, stream>>>(w_qkv, Wqh, Wql, D, 3 * D);
    split_tr<<<dim3(D / 32, D / 32), 256, 0, stream>>>(w_out, Woh, Wol, D, D);

    // BM=128, BN=256: QKV 12x64=768 blocks (3 full CU rounds), both %8==0
    gemm_split<true><<<dim3(3 * D / 256, MROWS / 128), 256, 0, stream>>>(
        Xhi, Xlo, Wqh, Wql, QKV, MROWS, 3 * D, D);

    attn_mfma<<<dim3(T / 128, B * NH), 512, 0, stream>>>(QKV, Xhi, Xlo);

    // out-proj: 4x64=256 blocks = exactly one full CU round
    gemm_split<false><<<dim3(D / 256, MROWS / 128), 256, 0, stream>>>(
        Xhi, Xlo, Woh, Wol, d_out, MROWS, D, D);
}

// Round 15
// 356.723 us; speedup vs baseline: 1.1080x; 1.1080x over previous
//
#include <hip/hip_runtime.h>

#define B  4
#define T  2048
#define D  1024
#define NH 16
#define DH 64
#define MROWS (B*T)   // 8192

typedef __attribute__((ext_vector_type(8))) short bf16x8;
typedef __attribute__((ext_vector_type(4))) float f32x4;
typedef __attribute__((ext_vector_type(4))) unsigned short u16x4;
typedef __attribute__((address_space(1))) const void gvoid;
typedef __attribute__((address_space(3))) void lvoid;

#define C_EXP 0.18033688011112042f   // 0.125 * log2(e)
// V-tile swizzle: must spread when dh = 4*lq+j (write) AND dh = dt*16+lq (read)
#define VSWZ(dh) (((((dh) ^ ((dh) >> 2)) & 7)) << 4)

__device__ inline unsigned short f2bf(float f) {
    union { float f; unsigned int u; } v; v.f = f;
    unsigned int r = v.u + 0x7fff + ((v.u >> 16) & 1);   // RNE
    return (unsigned short)(r >> 16);
}
__device__ inline float bf2f(unsigned short u) {
    union { unsigned int u; float f; } v; v.u = ((unsigned int)u) << 16;
    return v.f;
}
__device__ inline float exp2_fast(float x) {
    float r;
    asm("v_exp_f32 %0, %1" : "=v"(r) : "v"(x));   // D = 2^S0
    return r;
}

// ---------------------------------------------------------------------------
// Split fp32 array into bf16 hi + bf16 lo (lo = bf16(x - hi)).
// ---------------------------------------------------------------------------
__global__ __launch_bounds__(256)
void split_f32(const float* __restrict__ in, unsigned short* __restrict__ hi,
               unsigned short* __restrict__ lo, int n4) {
    for (int i = blockIdx.x * 256 + threadIdx.x; i < n4; i += gridDim.x * 256) {
        const float4 v = ((const float4*)in)[i];
        ushort4 h, l;
        h.x = f2bf(v.x); l.x = f2bf(v.x - bf2f(h.x));
        h.y = f2bf(v.y); l.y = f2bf(v.y - bf2f(h.y));
        h.z = f2bf(v.z); l.z = f2bf(v.z - bf2f(h.z));
        h.w = f2bf(v.w); l.w = f2bf(v.w - bf2f(h.w));
        ((ushort4*)hi)[i] = h;
        ((ushort4*)lo)[i] = l;
    }
}

// ---------------------------------------------------------------------------
// Transpose (K x N fp32) -> (N x K) bf16 hi/lo, 32x32 LDS tiles.
// ---------------------------------------------------------------------------
__global__ __launch_bounds__(256)
void split_tr(const float* __restrict__ Wm, unsigned short* __restrict__ hi,
              unsigned short* __restrict__ lo, int K, int N) {
    __shared__ float Tl[32][36];
    const int nt = blockIdx.x * 32, kt = blockIdx.y * 32;
    const int t = threadIdx.x;
    {
        const int r = t >> 3, c = (t & 7) * 4;
        const float4 v = *(const float4*)&Wm[(size_t)(kt + r) * N + nt + c];
        Tl[r][c] = v.x; Tl[r][c + 1] = v.y; Tl[r][c + 2] = v.z; Tl[r][c + 3] = v.w;
    }
    __syncthreads();
    {
        const int nl = t >> 3, k4 = (t & 7) * 4;
        const float v0 = Tl[k4 + 0][nl], v1 = Tl[k4 + 1][nl];
        const float v2 = Tl[k4 + 2][nl], v3 = Tl[k4 + 3][nl];
        ushort4 h, l;
        h.x = f2bf(v0); l.x = f2bf(v0 - bf2f(h.x));
        h.y = f2bf(v1); l.y = f2bf(v1 - bf2f(h.y));
        h.z = f2bf(v2); l.z = f2bf(v2 - bf2f(h.z));
        h.w = f2bf(v3); l.w = f2bf(v3 - bf2f(h.w));
        const size_t o = (size_t)(nt + nl) * K + kt + k4;
        *(ushort4*)&hi[o] = h;
        *(ushort4*)&lo[o] = l;
    }
}

// ---------------------------------------------------------------------------
// Split-bf16 MFMA GEMM: C = A@B, 3 MFMA passes (hi*hi + hi*lo + lo*hi).
// A ~ Ahi+Alo (MxK), B^T ~ Bthi+Btlo (NxK). BM=256, BN=128, BK=32,
// 8 waves (4M x 2N), per-wave 64x64, 96KB dbuf -> 8 resident waves
// (2/SIMD). NO intra-tile barriers: after the single per-K-tile
// __syncthreads, waves free-run {A-frag reads, stream 4x(2 B-reads ->
// 12 MFMA)} so the LDS port and MFMA pipe overlap across waves instead
// of lockstep-serializing (rounds 8/9/11 all pinned at 44% MfmaUtil).
// ---------------------------------------------------------------------------
template<bool OUT_BF16>
__global__ __launch_bounds__(512, 2)
void gemm_split(const unsigned short* __restrict__ Ahi, const unsigned short* __restrict__ Alo,
                const unsigned short* __restrict__ Bthi, const unsigned short* __restrict__ Btlo,
                void* __restrict__ Cout, int M, int N, int K) {
    __shared__ unsigned char As[2][256 * 128];   // 256 rows x (hi 64B | lo 64B)
    __shared__ unsigned char Bs[2][128 * 128];   // 128 rows x (hi 64B | lo 64B)
    const int tid  = threadIdx.x;
    const int w    = tid >> 6;        // 0..7
    const int lane = tid & 63;
    const int lq   = lane & 15;
    const int lk   = lane >> 4;
    const int wm   = w >> 1;          // 0..3 -> 64-row band
    const int wn   = w & 1;           // 0..1 -> 64-col band

    // XCD-aware bijective swizzle (nwg % 8 == 0 for both launches).
    const int gx  = gridDim.x;
    const int nwg = gx * gridDim.y;
    int lin = blockIdx.y * gx + blockIdx.x;
    lin = (lin & 7) * (nwg >> 3) + (lin >> 3);
    const int bm = (lin / gx) * 256;
    const int bn = (lin % gx) * 128;

    // pre-swizzled staging source pattern: lane l -> LDS (row=l>>3, slot=l&7);
    // content must be chunk (slot ^ row) of that row (rows 8-aligned).
    const int srow   = lane >> 3;
    const int sidx   = (lane & 7) ^ srow;   // 0..7: 0-3 = hi chunks, 4-7 = lo
    const int shalf  = sidx >> 2;
    const int schunk = sidx & 3;
    const unsigned short* aPtr = (shalf ? Alo : Ahi) + (size_t)(bm + w * 32 + srow) * K + schunk * 8;
    const unsigned short* bPtr = (shalf ? Btlo : Bthi) + (size_t)(bn + w * 16 + srow) * K + schunk * 8;

    f32x4 acc[4][4];
    #pragma unroll
    for (int m = 0; m < 4; ++m)
        #pragma unroll
        for (int n = 0; n < 4; ++n) acc[m][n] = f32x4{0.f, 0.f, 0.f, 0.f};

    // ---- prologue: stage K-tile 0 into buffer 0 (A: 4 instr, B: 2 instr) ----
    #pragma unroll
    for (int i = 0; i < 4; ++i)
        __builtin_amdgcn_global_load_lds((gvoid*)(aPtr + (size_t)i * 8 * K),
                                         (lvoid*)&As[0][(w * 32 + i * 8) * 128], 16, 0, 0);
    #pragma unroll
    for (int i = 0; i < 2; ++i)
        __builtin_amdgcn_global_load_lds((gvoid*)(bPtr + (size_t)i * 8 * K),
                                         (lvoid*)&Bs[0][(w * 16 + i * 8) * 128], 16, 0, 0);
    __syncthreads();

    int cur = 0;
    for (int k0 = 0; k0 < K; k0 += 32) {
        // ---- issue next-tile staging early (hides under this tile's MFMA) ----
        if (k0 + 32 < K) {
            #pragma unroll
            for (int i = 0; i < 4; ++i)
                __builtin_amdgcn_global_load_lds(
                    (gvoid*)(aPtr + (size_t)i * 8 * K + k0 + 32),
                    (lvoid*)&As[cur ^ 1][(w * 32 + i * 8) * 128], 16, 0, 0);
            #pragma unroll
            for (int i = 0; i < 2; ++i)
                __builtin_amdgcn_global_load_lds(
                    (gvoid*)(bPtr + (size_t)i * 8 * K + k0 + 32),
                    (lvoid*)&Bs[cur ^ 1][(w * 16 + i * 8) * 128], 16, 0, 0);
        }

        // ---- A fragments (held in VGPR, reused over the 4 n sub-tiles) ----
        bf16x8 ah[4], al[4];
        #pragma unroll
        for (int m = 0; m < 4; ++m) {
            const int row = wm * 64 + m * 16 + lq;
            const int sw  = row & 7;
            ah[m] = *(const bf16x8*)&As[cur][row * 128 + ((lk ^ sw) << 4)];
            al[m] = *(const bf16x8*)&As[cur][row * 128 + (((4 + lk) ^ sw) << 4)];
        }
        // ---- stream over 4 B sub-tiles: 2 ds_reads -> 12 MFMA each ----
        #pragma unroll
        for (int n = 0; n < 4; ++n) {
            const int row = wn * 64 + n * 16 + lq;
            const int sw  = row & 7;
            const bf16x8 bh = *(const bf16x8*)&Bs[cur][row * 128 + ((lk ^ sw) << 4)];
            const bf16x8 bl = *(const bf16x8*)&Bs[cur][row * 128 + (((4 + lk) ^ sw) << 4)];
            #pragma unroll
            for (int m = 0; m < 4; ++m) {
                acc[m][n] = __builtin_amdgcn_mfma_f32_16x16x32_bf16(ah[m], bh, acc[m][n], 0, 0, 0);
                acc[m][n] = __builtin_amdgcn_mfma_f32_16x16x32_bf16(ah[m], bl, acc[m][n], 0, 0, 0);
                acc[m][n] = __builtin_amdgcn_mfma_f32_16x16x32_bf16(al[m], bh, acc[m][n], 0, 0, 0);
            }
        }
        __syncthreads();   // single barrier: drains staging, protects buf reuse
        cur ^= 1;
    }

    #pragma unroll
    for (int m = 0; m < 4; ++m)
        #pragma unroll
        for (int ri = 0; ri < 4; ++ri) {
            const int row = bm + wm * 64 + m * 16 + lk * 4 + ri;
            #pragma unroll
            for (int n = 0; n < 4; ++n) {
                const int col = bn + wn * 64 + n * 16 + lq;
                if (OUT_BF16)
                    ((unsigned short*)Cout)[(size_t)row * N + col] = f2bf(acc[m][n][ri]);
                else
                    ((float*)Cout)[(size_t)row * N + col] = acc[m][n][ri];
            }
        }
}

// ---------------------------------------------------------------------------
// bf16-MFMA flash attention (unchanged). 8 waves, Q-tile 128, KV-tile 64,
// double-buffered K (global_load_lds) and V (reg-staged transpose).
// ---------------------------------------------------------------------------
__global__ __launch_bounds__(512)
void attn_mfma(const unsigned short* __restrict__ qkv,
               unsigned short* __restrict__ yhi, unsigned short* __restrict__ ylo) {
    const int bh  = blockIdx.y;
    const int b   = bh / NH;
    const int h   = bh % NH;
    const int qt  = blockIdx.x;           // Q-tile of 128 rows
    const int tid = threadIdx.x;
    const int w    = tid >> 6;            // 0..7
    const int lane = tid & 63;
    const int lq   = lane & 15;
    const int lk   = lane >> 4;

    __shared__ unsigned char Ks [2][64 * 128];  // bf16 [key][dh], swizzled, dbuf
    __shared__ unsigned char Vts[2][64 * 128];  // bf16 [dh][key], VSWZ, dbuf
    __shared__ unsigned char QPs[128 * 128];    // Q tile 128 rows; then P (8 x 2KB)

    // ---- stage Q (bf16 copy, swizzled): 1024 chunks of 16B, 512 thr x 2 ----
    #pragma unroll
    for (int it = 0; it < 2; ++it) {
        const int c   = tid + 512 * it;
        const int row = c >> 3, slot = c & 7;
        const bf16x8 v = *(const bf16x8*)&qkv[(size_t)(b * T + qt * 128 + row) * (3 * D) + h * DH + slot * 8];
        *(bf16x8*)&QPs[row * 128 + ((slot ^ (row & 7)) << 4)] = v;
    }

    // per-lane pre-swizzled source for K global_load_lds (1 instr/wave, 8 rows)
    const int srow   = lane >> 3;
    const int schunk = (lane & 7) ^ srow;
    const unsigned short* kBase = qkv + (size_t)(b * T + w * 8 + srow) * (3 * D) + D + h * DH + schunk * 8;
    // V staging: thread covers keys w*8+lk*2+{0,1}, dh lq*4..lq*4+3
    const unsigned short* vBase = qkv + (size_t)(b * T + w * 8 + lk * 2) * (3 * D) + 2 * D + h * DH + lq * 4;

    // ---- prologue: stage tile 0 into buffer 0 ----
    __builtin_amdgcn_global_load_lds((gvoid*)kBase, (lvoid*)&Ks[0][(w * 8) * 128], 16, 0, 0);
    u16x4 vr[2];
    #pragma unroll
    for (int i = 0; i < 2; ++i)
        vr[i] = *(const u16x4*)(vBase + (size_t)i * (3 * D));
    #pragma unroll
    for (int j = 0; j < 4; ++j) {
        const int dh = lq * 4 + j;
        const unsigned int pk = (unsigned int)vr[0][j] | ((unsigned int)vr[1][j] << 16);
        *(unsigned int*)&Vts[0][(dh * 128 + w * 16 + lk * 4) ^ VSWZ(dh)] = pk;
    }
    __syncthreads();

    // ---- Q fragments (wave w owns rows w*16..w*16+15) ----
    bf16x8 qf[2];
    #pragma unroll
    for (int ks = 0; ks < 2; ++ks) {
        const int row = w * 16 + lq;
        qf[ks] = *(const bf16x8*)&QPs[row * 128 + (((ks * 4 + lk) ^ (row & 7)) << 4)];
    }

    f32x4 o[4];
    #pragma unroll
    for (int dt = 0; dt < 4; ++dt) o[dt] = f32x4{0.f, 0.f, 0.f, 0.f};
    float m_r = -1e30f, l_r = 0.f;

    unsigned char* Pw = &QPs[w * 2048];

    for (int t = 0; t < T / 64; ++t) {
        const int c = t & 1;
        const bool more = (t + 1 < T / 64);
        // ---- issue next-tile staging early (hides under compute) ----
        if (more) {
            const int ktn = (t + 1) * 64;
            __builtin_amdgcn_global_load_lds((gvoid*)(kBase + (size_t)ktn * (3 * D)),
                                             (lvoid*)&Ks[c ^ 1][(w * 8) * 128], 16, 0, 0);
            #pragma unroll
            for (int i = 0; i < 2; ++i)
                vr[i] = *(const u16x4*)(vBase + (size_t)(ktn + i) * (3 * D));
        }

        // ---- S^T = K Q (swapped): lane owns 16 logits of query lq ----
        f32x4 s[4];
        #pragma unroll
        for (int ct = 0; ct < 4; ++ct) s[ct] = f32x4{0.f, 0.f, 0.f, 0.f};
        __builtin_amdgcn_s_setprio(1);
        #pragma unroll
        for (int ks = 0; ks < 2; ++ks) {
            #pragma unroll
            for (int ct = 0; ct < 4; ++ct) {
                const int key = ct * 16 + lq;
                const bf16x8 kf = *(const bf16x8*)&Ks[c][key * 128 + (((ks * 4 + lk) ^ (key & 7)) << 4)];
                s[ct] = __builtin_amdgcn_mfma_f32_16x16x32_bf16(kf, qf[ks], s[ct], 0, 0, 0);
            }
        }
        __builtin_amdgcn_s_setprio(0);

        // ---- online softmax (raw-logit domain) ----
        float v16 = s[0][0];
        #pragma unroll
        for (int ct = 0; ct < 4; ++ct)
            #pragma unroll
            for (int r = 0; r < 4; ++r) v16 = fmaxf(v16, s[ct][r]);
        v16 = fmaxf(v16, __shfl_xor(v16, 16));
        v16 = fmaxf(v16, __shfl_xor(v16, 32));
        if (__any(v16 > m_r)) {
            const float mnew = fmaxf(m_r, v16);
            const float corr = exp2_fast((m_r - mnew) * C_EXP);
            m_r = mnew;
            l_r *= corr;
            float corrO[4];
            #pragma unroll
            for (int r = 0; r < 4; ++r) corrO[r] = __shfl(corr, lk * 4 + r);
            #pragma unroll
            for (int dt = 0; dt < 4; ++dt)
                #pragma unroll
                for (int r = 0; r < 4; ++r) o[dt][r] *= corrO[r];
        }
        const float mC = m_r * C_EXP;
        float p[4][4];
        float tsum = 0.f;
        #pragma unroll
        for (int ct = 0; ct < 4; ++ct)
            #pragma unroll
            for (int r = 0; r < 4; ++r) {
                p[ct][r] = exp2_fast(__builtin_fmaf(s[ct][r], C_EXP, -mC));
                tsum += p[ct][r];
            }
        tsum += __shfl_xor(tsum, 16);
        tsum += __shfl_xor(tsum, 32);
        l_r += tsum;

        // ---- P pack (v_cvt_pk_bf16_f32) + 4x ds_write_b64 ----
        #pragma unroll
        for (int ct = 0; ct < 4; ++ct) {
            uint2 pk2;
            asm("v_cvt_pk_bf16_f32 %0, %1, %2" : "=v"(pk2.x) : "v"(p[ct][0]), "v"(p[ct][1]));
            asm("v_cvt_pk_bf16_f32 %0, %1, %2" : "=v"(pk2.y) : "v"(p[ct][2]), "v"(p[ct][3]));
            *(uint2*)&Pw[(lq * 128 + ct * 32 + lk * 8) ^ ((lq & 7) << 4)] = pk2;
        }
        asm volatile("s_waitcnt lgkmcnt(0)" ::: "memory");
        __builtin_amdgcn_sched_barrier(0);

        // ---- O += P V ----
        __builtin_amdgcn_s_setprio(1);
        #pragma unroll
        for (int ks = 0; ks < 2; ++ks) {
            const bf16x8 pf = *(const bf16x8*)&Pw[(lq * 128 + ks * 64 + lk * 16) ^ ((lq & 7) << 4)];
            #pragma unroll
            for (int dt = 0; dt < 4; ++dt) {
                const int dh = dt * 16 + lq;
                const bf16x8 vf = *(const bf16x8*)&Vts[c][(dh * 128 + ks * 64 + lk * 16) ^ VSWZ(dh)];
                o[dt] = __builtin_amdgcn_mfma_f32_16x16x32_bf16(pf, vf, o[dt], 0, 0, 0);
            }
        }
        __builtin_amdgcn_s_setprio(0);

        // ---- write next V tile into other buffer (vmcnt auto-waited) ----
        if (more) {
            #pragma unroll
            for (int j = 0; j < 4; ++j) {
                const int dh = lq * 4 + j;
                const unsigned int pk = (unsigned int)vr[0][j] | ((unsigned int)vr[1][j] << 16);
                *(unsigned int*)&Vts[c ^ 1][(dh * 128 + w * 16 + lk * 4) ^ VSWZ(dh)] = pk;
            }
        }
        __syncthreads();   // one barrier per tile
    }

    // ---- epilogue: O/l -> y hi/lo bf16 ----
    const float inv = 1.0f / l_r;
    float invO[4];
    #pragma unroll
    for (int r = 0; r < 4; ++r) invO[r] = __shfl(inv, lk * 4 + r);
    #pragma unroll
    for (int r = 0; r < 4; ++r) {
        const int row = qt * 128 + w * 16 + lk * 4 + r;
        const size_t base = (size_t)(b * T + row) * D + h * DH;
        #pragma unroll
        for (int dt = 0; dt < 4; ++dt) {
            const float val = o[dt][r] * invO[r];
            const unsigned short hv = f2bf(val);
            yhi[base + dt * 16 + lq] = hv;
            ylo[base + dt * 16 + lq] = f2bf(val - bf2f(hv));
        }
    }
}

// ---------------------------------------------------------------------------
extern "C" void kernel_launch(void* const* d_in, const int* in_sizes, int n_in,
                              void* d_out, int out_size, void* d_ws, size_t ws_size,
                              hipStream_t stream) {
    const float* x     = (const float*)d_in[0];
    const float* w_qkv = (const float*)d_in[1];
    const float* w_out = (const float*)d_in[2];

    unsigned short* Xhi = (unsigned short*)d_ws;              // M*D (reused as Yhi)
    unsigned short* Xlo = Xhi + (size_t)MROWS * D;            // M*D (reused as Ylo)
    unsigned short* Wqh = Xlo + (size_t)MROWS * D;            // 3D*D (N x K)
    unsigned short* Wql = Wqh + (size_t)3 * D * D;
    unsigned short* Woh = Wql + (size_t)3 * D * D;            // D*D
    unsigned short* Wol = Woh + (size_t)D * D;
    unsigned short* QKV = Wol + (size_t)D * D;                // M*3D bf16

    split_f32<<<2048, 256, 0, stream>>>(x, Xhi, Xlo, MROWS * D / 4);
    split_tr<<<dim3(3 * D / 32, D / 32), 256, 0, stream>>>(w_qkv, Wqh, Wql, D, 3 * D);
    split_tr<<<dim3(D / 32, D / 32), 256, 0, stream>>>(w_out, Woh, Wol, D, D);

    // BM=256, BN=128: QKV 24x32=768 blocks (3 full CU rounds), both %8==0
    gemm_split<true><<<dim3(3 * D / 128, MROWS / 256), 512, 0, stream>>>(
        Xhi, Xlo, Wqh, Wql, QKV, MROWS, 3 * D, D);

    attn_mfma<<<dim3(T / 128, B * NH), 512, 0, stream>>>(QKV, Xhi, Xlo);

    // out-proj: 8x32=256 blocks = exactly one full CU round
    gemm_split<false><<<dim3(D / 128, MROWS / 256), 512, 0, stream>>>(
        Xhi, Xlo, Woh, Wol, d_out, MROWS, D, D);
}

// Round 16
// 343.205 us; speedup vs baseline: 1.1516x; 1.0394x over previous
//
#include <hip/hip_runtime.h>

#define B  4
#define T  2048
#define D  1024
#define NH 16
#define DH 64
#define MROWS (B*T)   // 8192

typedef __attribute__((ext_vector_type(8))) short bf16x8;
typedef __attribute__((ext_vector_type(4))) float f32x4;
typedef __attribute__((ext_vector_type(4))) unsigned short u16x4;
typedef __attribute__((address_space(1))) const void gvoid;
typedef __attribute__((address_space(3))) void lvoid;

#define C_EXP 0.18033688011112042f   // 0.125 * log2(e)
// V-tile swizzle: must spread when dh = 4*lq+j (write) AND dh = dt*16+lq (read)
#define VSWZ(dh) (((((dh) ^ ((dh) >> 2)) & 7)) << 4)

__device__ inline unsigned short f2bf(float f) {
    union { float f; unsigned int u; } v; v.f = f;
    unsigned int r = v.u + 0x7fff + ((v.u >> 16) & 1);   // RNE
    return (unsigned short)(r >> 16);
}
__device__ inline float bf2f(unsigned short u) {
    union { unsigned int u; float f; } v; v.u = ((unsigned int)u) << 16;
    return v.f;
}
__device__ inline float exp2_fast(float x) {
    float r;
    asm("v_exp_f32 %0, %1" : "=v"(r) : "v"(x));   // D = 2^S0
    return r;
}

// ---------------------------------------------------------------------------
// Split fp32 array into bf16 hi + bf16 lo (lo = bf16(x - hi)).
// ---------------------------------------------------------------------------
__global__ __launch_bounds__(256)
void split_f32(const float* __restrict__ in, unsigned short* __restrict__ hi,
               unsigned short* __restrict__ lo, int n4) {
    for (int i = blockIdx.x * 256 + threadIdx.x; i < n4; i += gridDim.x * 256) {
        const float4 v = ((const float4*)in)[i];
        ushort4 h, l;
        h.x = f2bf(v.x); l.x = f2bf(v.x - bf2f(h.x));
        h.y = f2bf(v.y); l.y = f2bf(v.y - bf2f(h.y));
        h.z = f2bf(v.z); l.z = f2bf(v.z - bf2f(h.z));
        h.w = f2bf(v.w); l.w = f2bf(v.w - bf2f(h.w));
        ((ushort4*)hi)[i] = h;
        ((ushort4*)lo)[i] = l;
    }
}

// ---------------------------------------------------------------------------
// W (K x N fp32) -> MFMA-fragment-major bf16 hi/lo:
// frag(nt, kt) = 64 lanes x 16B contiguous (1 KB), lane l = (lk=l>>4, lq=l&15):
// elements W[kt*32 + lk*8 .. +8][nt*16 + lq]  (the exact B-operand fragment
// of mfma_f32_16x16x32). A wave's B-frag load becomes ONE coalesced
// global_load_dwordx4 of a contiguous 1 KB block (L2-resident).
// ---------------------------------------------------------------------------
__global__ __launch_bounds__(256)
void split_frag(const float* __restrict__ Wm, unsigned short* __restrict__ fh,
                unsigned short* __restrict__ fl, int K, int N) {
    const int l   = threadIdx.x & 63;
    const int nt  = blockIdx.x * 4 + (threadIdx.x >> 6);
    const int kt  = blockIdx.y;
    const int NKT = K / 32;
    const int n   = nt * 16 + (l & 15);
    const int k0  = kt * 32 + (l >> 4) * 8;
    bf16x8 hv, lv;
    #pragma unroll
    for (int j = 0; j < 8; ++j) {
        const float v = Wm[(size_t)(k0 + j) * N + n];
        const unsigned short h = f2bf(v);
        hv[j] = (short)h;
        lv[j] = (short)f2bf(v - bf2f(h));
    }
    const size_t o = ((size_t)nt * NKT + kt) * 512 + (size_t)l * 8;
    *(bf16x8*)&fh[o] = hv;
    *(bf16x8*)&fl[o] = lv;
}

// ---------------------------------------------------------------------------
// Split-bf16 MFMA GEMM, direct-global B: C = A@B, 3 MFMA passes
// (hi*hi + hi*lo + lo*hi). A ~ Ahi+Alo (MxK) staged in LDS (gload_lds,
// dbuf, pre-swizzled source); B read as fragment-major bf16 DIRECTLY from
// global into VGPRs (1 coalesced 1KB load per frag, L2-resident weights).
// This halves LDS-port reads per K-tile (16 -> 8 per wave) making the
// kernel MFMA-dominant instead of port-serialized (R8-R15 all ~44%).
// 128x128 tile, 4 waves (2x2), per-wave 64x64, 32 KB LDS, 3 blocks/CU.
// ---------------------------------------------------------------------------
template<bool OUT_BF16>
__global__ __launch_bounds__(256, 3)
void gemm_bdir(const unsigned short* __restrict__ Ahi, const unsigned short* __restrict__ Alo,
               const unsigned short* __restrict__ Bfh, const unsigned short* __restrict__ Bfl,
               void* __restrict__ Cout, int M, int N, int K) {
    __shared__ unsigned char As[2][128 * 128];   // 128 rows x (hi 64B | lo 64B)
    const int tid  = threadIdx.x;
    const int w    = tid >> 6;        // 0..3
    const int lane = tid & 63;
    const int lq   = lane & 15;
    const int lk   = lane >> 4;
    const int wm   = w >> 1;          // 0..1 -> 64-row band
    const int wn   = w & 1;           // 0..1 -> 64-col band
    const int NKT  = K / 32;

    // XCD-aware bijective swizzle (nwg % 8 == 0 for both launches).
    const int gx  = gridDim.x;
    const int nwg = gx * gridDim.y;
    int lin = blockIdx.y * gx + blockIdx.x;
    lin = (lin & 7) * (nwg >> 3) + (lin >> 3);
    const int bm = (lin / gx) * 128;
    const int bn = (lin % gx) * 128;

    // pre-swizzled A staging source (verified R8 pattern): lane l -> LDS
    // (row=l>>3, slot=l&7); content = chunk (slot ^ row) of that row.
    const int srow   = lane >> 3;
    const int sidx   = (lane & 7) ^ srow;   // 0..7: 0-3 = hi chunks, 4-7 = lo
    const int shalf  = sidx >> 2;
    const int schunk = sidx & 3;
    const unsigned short* aPtr = (shalf ? Alo : Ahi) + (size_t)(bm + w * 32 + srow) * K + schunk * 8;

    // per-wave B fragment bases (fragment-major layout)
    const unsigned short* bhBase = Bfh + ((size_t)(bn / 16 + wn * 4) * NKT) * 512 + (size_t)lane * 8;
    const unsigned short* blBase = Bfl + ((size_t)(bn / 16 + wn * 4) * NKT) * 512 + (size_t)lane * 8;

    f32x4 acc[4][4];
    #pragma unroll
    for (int m = 0; m < 4; ++m)
        #pragma unroll
        for (int n = 0; n < 4; ++n) acc[m][n] = f32x4{0.f, 0.f, 0.f, 0.f};

    // ---- prologue: stage A K-tile 0 into buffer 0 (4 instr/wave) ----
    #pragma unroll
    for (int i = 0; i < 4; ++i)
        __builtin_amdgcn_global_load_lds((gvoid*)(aPtr + (size_t)i * 8 * K),
                                         (lvoid*)&As[0][(w * 32 + i * 8) * 128], 16, 0, 0);
    __syncthreads();

    int cur = 0;
    for (int kt = 0; kt < NKT; ++kt) {
        // ---- stage next A tile early (hides under this tile's MFMA) ----
        if (kt + 1 < NKT) {
            #pragma unroll
            for (int i = 0; i < 4; ++i)
                __builtin_amdgcn_global_load_lds(
                    (gvoid*)(aPtr + (size_t)i * 8 * K + (kt + 1) * 32),
                    (lvoid*)&As[cur ^ 1][(w * 32 + i * 8) * 128], 16, 0, 0);
        }
        // ---- B fragments: direct coalesced global loads (L2-hot) ----
        bf16x8 bh[4], bl[4];
        #pragma unroll
        for (int n = 0; n < 4; ++n) {
            bh[n] = *(const bf16x8*)&bhBase[((size_t)n * NKT + kt) * 512];
            bl[n] = *(const bf16x8*)&blBase[((size_t)n * NKT + kt) * 512];
        }
        // ---- A fragments from LDS (8 ds_read_b128/wave) ----
        bf16x8 ah[4], al[4];
        #pragma unroll
        for (int m = 0; m < 4; ++m) {
            const int row = wm * 64 + m * 16 + lq;
            const int sw  = row & 7;
            ah[m] = *(const bf16x8*)&As[cur][row * 128 + ((lk ^ sw) << 4)];
            al[m] = *(const bf16x8*)&As[cur][row * 128 + (((4 + lk) ^ sw) << 4)];
        }
        __builtin_amdgcn_s_setprio(1);
        #pragma unroll
        for (int n = 0; n < 4; ++n)
            #pragma unroll
            for (int m = 0; m < 4; ++m) {
                acc[m][n] = __builtin_amdgcn_mfma_f32_16x16x32_bf16(ah[m], bh[n], acc[m][n], 0, 0, 0);
                acc[m][n] = __builtin_amdgcn_mfma_f32_16x16x32_bf16(ah[m], bl[n], acc[m][n], 0, 0, 0);
                acc[m][n] = __builtin_amdgcn_mfma_f32_16x16x32_bf16(al[m], bh[n], acc[m][n], 0, 0, 0);
            }
        __builtin_amdgcn_s_setprio(0);
        __syncthreads();   // drains A staging, protects buf reuse
        cur ^= 1;
    }

    #pragma unroll
    for (int m = 0; m < 4; ++m)
        #pragma unroll
        for (int ri = 0; ri < 4; ++ri) {
            const int row = bm + wm * 64 + m * 16 + lk * 4 + ri;
            #pragma unroll
            for (int n = 0; n < 4; ++n) {
                const int col = bn + wn * 64 + n * 16 + lq;
                if (OUT_BF16)
                    ((unsigned short*)Cout)[(size_t)row * N + col] = f2bf(acc[m][n][ri]);
                else
                    ((float*)Cout)[(size_t)row * N + col] = acc[m][n][ri];
            }
        }
}

// ---------------------------------------------------------------------------
// bf16-MFMA flash attention (unchanged, verified since R8). 8 waves,
// Q-tile 128, KV-tile 64, dbuf K (gload_lds) and V (reg-staged transpose).
// ---------------------------------------------------------------------------
__global__ __launch_bounds__(512)
void attn_mfma(const unsigned short* __restrict__ qkv,
               unsigned short* __restrict__ yhi, unsigned short* __restrict__ ylo) {
    const int bh  = blockIdx.y;
    const int b   = bh / NH;
    const int h   = bh % NH;
    const int qt  = blockIdx.x;           // Q-tile of 128 rows
    const int tid = threadIdx.x;
    const int w    = tid >> 6;            // 0..7
    const int lane = tid & 63;
    const int lq   = lane & 15;
    const int lk   = lane >> 4;

    __shared__ unsigned char Ks [2][64 * 128];  // bf16 [key][dh], swizzled, dbuf
    __shared__ unsigned char Vts[2][64 * 128];  // bf16 [dh][key], VSWZ, dbuf
    __shared__ unsigned char QPs[128 * 128];    // Q tile 128 rows; then P (8 x 2KB)

    // ---- stage Q (bf16 copy, swizzled): 1024 chunks of 16B, 512 thr x 2 ----
    #pragma unroll
    for (int it = 0; it < 2; ++it) {
        const int c   = tid + 512 * it;
        const int row = c >> 3, slot = c & 7;
        const bf16x8 v = *(const bf16x8*)&qkv[(size_t)(b * T + qt * 128 + row) * (3 * D) + h * DH + slot * 8];
        *(bf16x8*)&QPs[row * 128 + ((slot ^ (row & 7)) << 4)] = v;
    }

    // per-lane pre-swizzled source for K global_load_lds (1 instr/wave, 8 rows)
    const int srow   = lane >> 3;
    const int schunk = (lane & 7) ^ srow;
    const unsigned short* kBase = qkv + (size_t)(b * T + w * 8 + srow) * (3 * D) + D + h * DH + schunk * 8;
    // V staging: thread covers keys w*8+lk*2+{0,1}, dh lq*4..lq*4+3
    const unsigned short* vBase = qkv + (size_t)(b * T + w * 8 + lk * 2) * (3 * D) + 2 * D + h * DH + lq * 4;

    // ---- prologue: stage tile 0 into buffer 0 ----
    __builtin_amdgcn_global_load_lds((gvoid*)kBase, (lvoid*)&Ks[0][(w * 8) * 128], 16, 0, 0);
    u16x4 vr[2];
    #pragma unroll
    for (int i = 0; i < 2; ++i)
        vr[i] = *(const u16x4*)(vBase + (size_t)i * (3 * D));
    #pragma unroll
    for (int j = 0; j < 4; ++j) {
        const int dh = lq * 4 + j;
        const unsigned int pk = (unsigned int)vr[0][j] | ((unsigned int)vr[1][j] << 16);
        *(unsigned int*)&Vts[0][(dh * 128 + w * 16 + lk * 4) ^ VSWZ(dh)] = pk;
    }
    __syncthreads();

    // ---- Q fragments (wave w owns rows w*16..w*16+15) ----
    bf16x8 qf[2];
    #pragma unroll
    for (int ks = 0; ks < 2; ++ks) {
        const int row = w * 16 + lq;
        qf[ks] = *(const bf16x8*)&QPs[row * 128 + (((ks * 4 + lk) ^ (row & 7)) << 4)];
    }

    f32x4 o[4];
    #pragma unroll
    for (int dt = 0; dt < 4; ++dt) o[dt] = f32x4{0.f, 0.f, 0.f, 0.f};
    float m_r = -1e30f, l_r = 0.f;

    unsigned char* Pw = &QPs[w * 2048];

    for (int t = 0; t < T / 64; ++t) {
        const int c = t & 1;
        const bool more = (t + 1 < T / 64);
        // ---- issue next-tile staging early (hides under compute) ----
        if (more) {
            const int ktn = (t + 1) * 64;
            __builtin_amdgcn_global_load_lds((gvoid*)(kBase + (size_t)ktn * (3 * D)),
                                             (lvoid*)&Ks[c ^ 1][(w * 8) * 128], 16, 0, 0);
            #pragma unroll
            for (int i = 0; i < 2; ++i)
                vr[i] = *(const u16x4*)(vBase + (size_t)(ktn + i) * (3 * D));
        }

        // ---- S^T = K Q (swapped): lane owns 16 logits of query lq ----
        f32x4 s[4];
        #pragma unroll
        for (int ct = 0; ct < 4; ++ct) s[ct] = f32x4{0.f, 0.f, 0.f, 0.f};
        __builtin_amdgcn_s_setprio(1);
        #pragma unroll
        for (int ks = 0; ks < 2; ++ks) {
            #pragma unroll
            for (int ct = 0; ct < 4; ++ct) {
                const int key = ct * 16 + lq;
                const bf16x8 kf = *(const bf16x8*)&Ks[c][key * 128 + (((ks * 4 + lk) ^ (key & 7)) << 4)];
                s[ct] = __builtin_amdgcn_mfma_f32_16x16x32_bf16(kf, qf[ks], s[ct], 0, 0, 0);
            }
        }
        __builtin_amdgcn_s_setprio(0);

        // ---- online softmax (raw-logit domain) ----
        float v16 = s[0][0];
        #pragma unroll
        for (int ct = 0; ct < 4; ++ct)
            #pragma unroll
            for (int r = 0; r < 4; ++r) v16 = fmaxf(v16, s[ct][r]);
        v16 = fmaxf(v16, __shfl_xor(v16, 16));
        v16 = fmaxf(v16, __shfl_xor(v16, 32));
        if (__any(v16 > m_r)) {
            const float mnew = fmaxf(m_r, v16);
            const float corr = exp2_fast((m_r - mnew) * C_EXP);
            m_r = mnew;
            l_r *= corr;
            float corrO[4];
            #pragma unroll
            for (int r = 0; r < 4; ++r) corrO[r] = __shfl(corr, lk * 4 + r);
            #pragma unroll
            for (int dt = 0; dt < 4; ++dt)
                #pragma unroll
                for (int r = 0; r < 4; ++r) o[dt][r] *= corrO[r];
        }
        const float mC = m_r * C_EXP;
        float p[4][4];
        float tsum = 0.f;
        #pragma unroll
        for (int ct = 0; ct < 4; ++ct)
            #pragma unroll
            for (int r = 0; r < 4; ++r) {
                p[ct][r] = exp2_fast(__builtin_fmaf(s[ct][r], C_EXP, -mC));
                tsum += p[ct][r];
            }
        tsum += __shfl_xor(tsum, 16);
        tsum += __shfl_xor(tsum, 32);
        l_r += tsum;

        // ---- P pack (v_cvt_pk_bf16_f32) + 4x ds_write_b64 ----
        #pragma unroll
        for (int ct = 0; ct < 4; ++ct) {
            uint2 pk2;
            asm("v_cvt_pk_bf16_f32 %0, %1, %2" : "=v"(pk2.x) : "v"(p[ct][0]), "v"(p[ct][1]));
            asm("v_cvt_pk_bf16_f32 %0, %1, %2" : "=v"(pk2.y) : "v"(p[ct][2]), "v"(p[ct][3]));
            *(uint2*)&Pw[(lq * 128 + ct * 32 + lk * 8) ^ ((lq & 7) << 4)] = pk2;
        }
        asm volatile("s_waitcnt lgkmcnt(0)" ::: "memory");
        __builtin_amdgcn_sched_barrier(0);

        // ---- O += P V ----
        __builtin_amdgcn_s_setprio(1);
        #pragma unroll
        for (int ks = 0; ks < 2; ++ks) {
            const bf16x8 pf = *(const bf16x8*)&Pw[(lq * 128 + ks * 64 + lk * 16) ^ ((lq & 7) << 4)];
            #pragma unroll
            for (int dt = 0; dt < 4; ++dt) {
                const int dh = dt * 16 + lq;
                const bf16x8 vf = *(const bf16x8*)&Vts[c][(dh * 128 + ks * 64 + lk * 16) ^ VSWZ(dh)];
                o[dt] = __builtin_amdgcn_mfma_f32_16x16x32_bf16(pf, vf, o[dt], 0, 0, 0);
            }
        }
        __builtin_amdgcn_s_setprio(0);

        // ---- write next V tile into other buffer (vmcnt auto-waited) ----
        if (more) {
            #pragma unroll
            for (int j = 0; j < 4; ++j) {
                const int dh = lq * 4 + j;
                const unsigned int pk = (unsigned int)vr[0][j] | ((unsigned int)vr[1][j] << 16);
                *(unsigned int*)&Vts[c ^ 1][(dh * 128 + w * 16 + lk * 4) ^ VSWZ(dh)] = pk;
            }
        }
        __syncthreads();   // one barrier per tile
    }

    // ---- epilogue: O/l -> y hi/lo bf16 ----
    const float inv = 1.0f / l_r;
    float invO[4];
    #pragma unroll
    for (int r = 0; r < 4; ++r) invO[r] = __shfl(inv, lk * 4 + r);
    #pragma unroll
    for (int r = 0; r < 4; ++r) {
        const int row = qt * 128 + w * 16 + lk * 4 + r;
        const size_t base = (size_t)(b * T + row) * D + h * DH;
        #pragma unroll
        for (int dt = 0; dt < 4; ++dt) {
            const float val = o[dt][r] * invO[r];
            const unsigned short hv = f2bf(val);
            yhi[base + dt * 16 + lq] = hv;
            ylo[base + dt * 16 + lq] = f2bf(val - bf2f(hv));
        }
    }
}

// ---------------------------------------------------------------------------
extern "C" void kernel_launch(void* const* d_in, const int* in_sizes, int n_in,
                              void* d_out, int out_size, void* d_ws, size_t ws_size,
                              hipStream_t stream) {
    const float* x     = (const float*)d_in[0];
    const float* w_qkv = (const float*)d_in[1];
    const float* w_out = (const float*)d_in[2];

    unsigned short* Xhi = (unsigned short*)d_ws;              // M*D (reused as Yhi)
    unsigned short* Xlo = Xhi + (size_t)MROWS * D;            // M*D (reused as Ylo)
    unsigned short* Wqh = Xlo + (size_t)MROWS * D;            // 3D*D frag-major
    unsigned short* Wql = Wqh + (size_t)3 * D * D;
    unsigned short* Woh = Wql + (size_t)3 * D * D;            // D*D frag-major
    unsigned short* Wol = Woh + (size_t)D * D;
    unsigned short* QKV = Wol + (size_t)D * D;                // M*3D bf16

    split_f32<<<2048, 256, 0, stream>>>(x, Xhi, Xlo, MROWS * D / 4);
    split_frag<<<dim3(3 * D / 64, D / 32), 256, 0, stream>>>(w_qkv, Wqh, Wql, D, 3 * D);
    split_frag<<<dim3(D / 64, D / 32), 256, 0, stream>>>(w_out, Woh, Wol, D, D);

    // QKV: 24x64 = 1536 blocks (6 full CU rounds), %8==0
    gemm_bdir<true><<<dim3(3 * D / 128, MROWS / 128), 256, 0, stream>>>(
        Xhi, Xlo, Wqh, Wql, QKV, MROWS, 3 * D, D);

    attn_mfma<<<dim3(T / 128, B * NH), 512, 0, stream>>>(QKV, Xhi, Xlo);

    // out-proj: 8x64 = 512 blocks (2 full CU rounds), %8==0
    gemm_bdir<false><<<dim3(D / 128, MROWS / 128), 256, 0, stream>>>(
        Xhi, Xlo, Woh, Wol, d_out, MROWS, D, D);
}